// Round 1
// baseline (100.752 us; speedup 1.0000x reference)
//
#include <hip/hip_runtime.h>
#include <math.h>

#define N1 16384
#define N2 16384
#define BLOCK 256
#define PTS 8                          // pos1 points per thread
#define KK (PTS / 2)                   // packed pairs of pos1 points
#define I_BLOCKS (N1 / (BLOCK * PTS))  // 8 blocks along pos1
#define SLICES 128                     // pos2 slices -> 1024 blocks, 4 waves/SIMD

typedef float v2f __attribute__((ext_vector_type(2)));

// Stage 1: for each pos1 point, min over one pos2 slice of
// g(q) = -2 p.q + |q|^2  (d^2 = |p|^2 + g, shift applied in stage 2).
// pos1 coords are pre-scaled by -2 once per thread, so per-j setup is only
// the two |q|^2 fmas. pos1 points are packed pairwise into v2f so the two
// fmas per pair become v_pk_fma_f32 (gfx950 packed-fp32) covering 2 pairs.
// Cross-slice combine: plain coalesced stores of per-slice partial minima
// (8 MB, L3-resident) -- no atomics, no key init memset.
__global__ __launch_bounds__(BLOCK, 4)
void nn_partial(const float2* __restrict__ pos1,
                const float4* __restrict__ pos2,   // 2 points per float4
                float* __restrict__ partials,
                unsigned int* __restrict__ ticket,
                int slice_f4) {
    const int ib = blockIdx.x;
    const int sl = blockIdx.y;
    const int t  = threadIdx.x;

    if (ib == 0 && sl == 0 && t == 0) *ticket = 0;  // init for stage 2

    const float4* __restrict__ q = pos2 + (size_t)sl * slice_f4;
    const int i0 = ib * (BLOCK * PTS) + t;

    v2f x2[KK], y2[KK], m2[KK];
#pragma unroll
    for (int k = 0; k < KK; ++k) {
        float2 p0 = pos1[i0 + (2 * k) * BLOCK];
        float2 p1 = pos1[i0 + (2 * k + 1) * BLOCK];
        x2[k] = (v2f){-2.f * p0.x, -2.f * p1.x};   // fold -2 into p
        y2[k] = (v2f){-2.f * p0.y, -2.f * p1.y};
        m2[k] = (v2f){3.4e38f, 3.4e38f};
    }

#pragma unroll 4
    for (int j = 0; j < slice_f4; ++j) {
        float4 qq = q[j];                          // uniform address, 2 pos2 pts
        float az = fmaf(qq.x, qq.x, qq.y * qq.y);  // |qa|^2
        float bz = fmaf(qq.z, qq.z, qq.w * qq.w);  // |qb|^2
        v2f AX = {qq.x, qq.x}, AY = {qq.y, qq.y}, AZ = {az, az};
        v2f BX = {qq.z, qq.z}, BY = {qq.w, qq.w}, BZ = {bz, bz};
#pragma unroll
        for (int k = 0; k < KK; ++k) {
            v2f ta = __builtin_elementwise_fma(
                x2[k], AX, __builtin_elementwise_fma(y2[k], AY, AZ));
            v2f tb = __builtin_elementwise_fma(
                x2[k], BX, __builtin_elementwise_fma(y2[k], BY, BZ));
            m2[k][0] = fminf(m2[k][0], fminf(ta[0], tb[0]));
            m2[k][1] = fminf(m2[k][1], fminf(ta[1], tb[1]));
        }
    }

    float* dst = partials + (size_t)sl * N1 + i0;
#pragma unroll
    for (int k = 0; k < KK; ++k) {                 // coalesced across t
        dst[(2 * k) * BLOCK]     = m2[k][0];
        dst[(2 * k + 1) * BLOCK] = m2[k][1];
    }
}

// Stage 2 (fused final): 64 blocks; min over SLICES partials, + |p|^2, sqrt,
// block-sum; last block (ticket) reduces the 64 block sums, writes the mean.
__global__ __launch_bounds__(BLOCK)
void nn_finish(const float* __restrict__ partials,
               const float2* __restrict__ pos1,
               float* __restrict__ blocksums,
               unsigned int* __restrict__ ticket,
               float* __restrict__ out) {
    const int t = threadIdx.x;
    const int i = blockIdx.x * BLOCK + t;

    float g = 3.4e38f;
#pragma unroll 16
    for (int sl = 0; sl < SLICES; ++sl) {          // coalesced per-lane, L3-hit
        g = fminf(g, partials[(size_t)sl * N1 + i]);
    }

    float2 p = pos1[i];
    float d2 = fmaxf(fmaf(p.x, p.x, p.y * p.y) + g, 0.f);
    float sum = sqrtf(d2);

    for (int off = 32; off > 0; off >>= 1) {
        sum += __shfl_down(sum, off, 64);
    }
    __shared__ float wsum[BLOCK / 64];
    __shared__ int lastflag;
    if ((t & 63) == 0) wsum[t >> 6] = sum;
    __syncthreads();
    if (t == 0) {
        float s = 0.f;
        for (int w = 0; w < BLOCK / 64; ++w) s += wsum[w];
        blocksums[blockIdx.x] = s;
        __threadfence();
        unsigned int old = atomicAdd(ticket, 1u);
        lastflag = (old == gridDim.x - 1) ? 1 : 0;
    }
    __syncthreads();
    if (lastflag && t < 64) {
        volatile float* vb = (volatile float*)blocksums;
        float v = vb[t];
        for (int off = 32; off > 0; off >>= 1) {
            v += __shfl_down(v, off, 64);
        }
        if (t == 0) out[0] = v / (float)N1;
    }
}

extern "C" void kernel_launch(void* const* d_in, const int* in_sizes, int n_in,
                              void* d_out, int out_size, void* d_ws, size_t ws_size,
                              hipStream_t stream) {
    const float2* pos1 = (const float2*)d_in[0];
    const float4* pos2 = (const float4*)d_in[1];
    float* out = (float*)d_out;

    float* partials      = (float*)d_ws;                    // N1*SLICES floats (8 MB)
    float* blocksums     = partials + (size_t)N1 * SLICES;  // 64 floats
    unsigned int* ticket = (unsigned int*)(blocksums + 64); // 1 uint

    const int slice_f4 = (N2 / SLICES) / 2;  // float4s per slice (64)

    dim3 grid1(I_BLOCKS, SLICES);
    nn_partial<<<grid1, BLOCK, 0, stream>>>(pos1, pos2, partials, ticket, slice_f4);
    nn_finish<<<N1 / BLOCK, BLOCK, 0, stream>>>(partials, pos1, blocksums, ticket, out);
}

// Round 2
// 81.392 us; speedup vs baseline: 1.2379x; 1.2379x over previous
//
#include <hip/hip_runtime.h>
#include <math.h>

#define N1 16384
#define N2 16384
#define BLOCK 256
#define PTS 8                          // pos1 points per thread
#define I_BLOCKS (N1 / (BLOCK * PTS))  // 8 blocks along pos1
#define SLICES 128                     // pos2 slices -> 1024 blocks, 4 waves/SIMD

// order-preserving float<->uint mapping (for atomicMin over possibly-negative g)
__device__ __forceinline__ unsigned int f2key(float f) {
    unsigned int b = __float_as_uint(f);
    return (b & 0x80000000u) ? ~b : (b | 0x80000000u);
}
__device__ __forceinline__ float key2f(unsigned int k) {
    unsigned int b = (k & 0x80000000u) ? (k & 0x7FFFFFFFu) : ~k;
    return __uint_as_float(b);
}

// Stage 1: for each pos1 point, min over one pos2 slice of
// g(q) = -2 p.q + |q|^2  (d^2 = |p|^2 + g, shift applied in stage 2).
// pos1 coords are pre-scaled by -2 ONCE per thread (exact, power of 2), so
// per-j setup is only az/bz (|q|^2): 4 VALU instead of 8. Inner per point:
// 2 fma + nested fminf -> v_min3_f32 fusion: 5 VALU / point-pair-pair.
// Cross-slice combine is the round-0-proven fire-and-forget device-scope
// atomicMin on a 64 KB key array.
__global__ __launch_bounds__(BLOCK, 4)
void nn_partial(const float2* __restrict__ pos1,
                const float4* __restrict__ pos2,   // 2 points per float4
                unsigned int* __restrict__ keys,
                unsigned int* __restrict__ ticket,
                int slice_f4) {
    const int ib = blockIdx.x;
    const int sl = blockIdx.y;
    const int t  = threadIdx.x;

    if (ib == 0 && sl == 0 && t == 0) *ticket = 0;  // init for stage 2

    const float4* __restrict__ q = pos2 + (size_t)sl * slice_f4;
    const int i0 = ib * (BLOCK * PTS) + t;

    float x[PTS], y[PTS], m[PTS];
#pragma unroll
    for (int k = 0; k < PTS; ++k) {
        float2 p = pos1[i0 + k * BLOCK];
        x[k] = -2.f * p.x;   // fold -2 into p (exact)
        y[k] = -2.f * p.y;
        m[k] = 3.4e38f;
    }

#pragma unroll 4
    for (int j = 0; j < slice_f4; ++j) {
        float4 qq = q[j];                          // uniform address, 2 pos2 pts
        float az = fmaf(qq.x, qq.x, qq.y * qq.y);  // |qa|^2
        float bz = fmaf(qq.z, qq.z, qq.w * qq.w);  // |qb|^2
#pragma unroll
        for (int k = 0; k < PTS; ++k) {
            float ta = fmaf(x[k], qq.x, fmaf(y[k], qq.y, az));
            float tb = fmaf(x[k], qq.z, fmaf(y[k], qq.w, bz));
            m[k] = fminf(m[k], fminf(ta, tb));     // -> v_min3_f32
        }
    }

#pragma unroll
    for (int k = 0; k < PTS; ++k) {
        atomicMin(&keys[i0 + k * BLOCK], f2key(m[k]));  // fire-and-forget
    }
}

// Stage 2 (fused final): 64 blocks; decode key, + |p|^2, sqrt, block-sum;
// last block (ticket) reduces the 64 block sums and writes the mean.
__global__ __launch_bounds__(BLOCK)
void nn_finish(const unsigned int* __restrict__ keys,
               const float2* __restrict__ pos1,
               float* __restrict__ blocksums,
               unsigned int* __restrict__ ticket,
               float* __restrict__ out) {
    const int t = threadIdx.x;
    const int i = blockIdx.x * BLOCK + t;

    float g = key2f(keys[i]);
    float2 p = pos1[i];
    float d2 = fmaxf(fmaf(p.x, p.x, p.y * p.y) + g, 0.f);
    float sum = sqrtf(d2);

    for (int off = 32; off > 0; off >>= 1) {
        sum += __shfl_down(sum, off, 64);
    }
    __shared__ float wsum[BLOCK / 64];
    __shared__ int lastflag;
    if ((t & 63) == 0) wsum[t >> 6] = sum;
    __syncthreads();
    if (t == 0) {
        float s = 0.f;
        for (int w = 0; w < BLOCK / 64; ++w) s += wsum[w];
        blocksums[blockIdx.x] = s;
        __threadfence();
        unsigned int old = atomicAdd(ticket, 1u);
        lastflag = (old == gridDim.x - 1) ? 1 : 0;
    }
    __syncthreads();
    if (lastflag && t < 64) {
        volatile float* vb = (volatile float*)blocksums;
        float v = vb[t];
        for (int off = 32; off > 0; off >>= 1) {
            v += __shfl_down(v, off, 64);
        }
        if (t == 0) out[0] = v / (float)N1;
    }
}

extern "C" void kernel_launch(void* const* d_in, const int* in_sizes, int n_in,
                              void* d_out, int out_size, void* d_ws, size_t ws_size,
                              hipStream_t stream) {
    const float2* pos1 = (const float2*)d_in[0];
    const float4* pos2 = (const float4*)d_in[1];
    float* out = (float*)d_out;

    unsigned int* keys = (unsigned int*)d_ws;               // N1 uints (64 KB)
    float* blocksums   = (float*)(keys + N1);               // 64 floats
    unsigned int* ticket = (unsigned int*)(blocksums + 64); // 1 uint

    const int slice_f4 = (N2 / SLICES) / 2;  // float4s per slice (64)

    // init keys to +inf ordering (0xFFFFFFFF)
    hipMemsetAsync(keys, 0xFF, (size_t)N1 * sizeof(unsigned int), stream);

    dim3 grid1(I_BLOCKS, SLICES);
    nn_partial<<<grid1, BLOCK, 0, stream>>>(pos1, pos2, keys, ticket, slice_f4);
    nn_finish<<<N1 / BLOCK, BLOCK, 0, stream>>>(keys, pos1, blocksums, ticket, out);
}